// Round 11
// baseline (392.970 us; speedup 1.0000x reference)
//
#include <hip/hip_runtime.h>
#include <stdint.h>
#include <math.h>

// HierarchicalSoftmax: out[b, i*225+j] = softmax(x@W0+b0)[b,i] * softmax(x@W1+b1)[b,j], f<50257
//
// Pipeline (R11: gemm = R9 verbatim (best measured). prep rewritten with coalesced W reads +
//           LDS fp32 transpose (was 900B-stride column gather, ~4x overfetch). finish rewritten
//           with float4 stores + 4 rotated h1 copies in LDS (stride 227: groups hit disjoint
//           bank cosets -> 2-way = free; fixes R8's 8-way conflict)):
//  1) hs_prep : W0,W1 fp32 [K][225] -> ws: per-K-tile images of W^T [480][128B] fp16 (x1024),
//               row-XOR-swizzled (16B-block ^= row&7).
//  2) hs_gemm : logits*1024 = (fp16)x @ (fp16)([W0|W1]*1024), fp32 acc, split-K partials.
//  3) hs_finish: reduce partials * 2^-10 + bias, per-head softmax, outer-product float4 store.

#define BATCH   2048
#define KDIM    50257
#define LSZ     225
#define HOFF    240        // head1 column offset in padded logits
#define NPAD    480        // padded N: [0,225) = head0, [240,465) = head1, rest zero
#define BK      64
#define BM      128
#define NT      786        // ceil(50257/64)
#define TILE_B  61440      // B tile bytes: 480 rows * 128B (fp16)
#define A_BYTES 16384      // A tile bytes: 128 rows * 128B (fp16)
#define BUF_B   77824      // TILE_B + A_BYTES
#define LDS_TOT 155648     // 2 * BUF_B (double buffer)
#define WSCALE  1024.0f    // W pre-scale: keeps fp16 weights out of denormal range

typedef __attribute__((ext_vector_type(8))) _Float16 f16x8;
typedef __attribute__((ext_vector_type(4))) float    f32x4;

__device__ __forceinline__ unsigned short f2h(float f) {    // fp32 -> fp16 bits (RNE)
  return __builtin_bit_cast(unsigned short, (_Float16)f);
}
// 128B-row swizzle: XOR 16B-block index by (row&7) -> 16-row frag reads = 2-way (free)
__device__ __forceinline__ int swz8(int r) { return (r & 7) << 4; }

// ---------------- prep: coalesced W read -> LDS transpose -> swizzled fp16 tile ----------------
__global__ __launch_bounds__(512) void hs_prep(const float* __restrict__ W0,
                                               const float* __restrict__ W1,
                                               unsigned char* __restrict__ wt) {
  const int kt = blockIdx.x;           // one K-tile (64 k's) per block
  const int k0 = kt * BK;
  const int tid = threadIdx.x;
  __shared__ float wl[64 * 227];       // 64 k-rows x 225 cols, pad->227 (transpose reads 2-way)
  unsigned char* tb = wt + (size_t)kt * TILE_B;

  for (int half = 0; half < 2; ++half) {
    const float* W = half ? W1 : W0;
    const int nbase = half * HOFF;
    // coalesced load: 64 contiguous rows of W (scaled), zero-pad k >= KDIM
    for (int u = tid; u < 64 * 225; u += 512) {
      const int k = u / 225;           // consecutive u -> consecutive addresses
      const int n = u - 225 * k;
      const float v = (k0 + k < KDIM) ? W[(size_t)(k0 + k) * 225 + n] * WSCALE : 0.0f;
      wl[k * 227 + n] = v;
    }
    __syncthreads();
    // transposed write: unit (n, c8) emits 8 k's of column n as a swizzled 16B block
    for (int u = tid; u < 240 * 8; u += 512) {
      const int n = u >> 3, c8 = u & 7;
      unsigned short he[8];
      if (n < LSZ) {
#pragma unroll
        for (int e = 0; e < 8; ++e)
          he[e] = f2h(wl[(c8 * 8 + e) * 227 + n]);
      } else {
#pragma unroll
        for (int e = 0; e < 8; ++e) he[e] = 0;
      }
      const int row = nbase + n;
      const int jp = (c8 * 16) ^ swz8(row);
      *(ushort4*)(tb + row * 128 + jp)     = make_ushort4(he[0], he[1], he[2], he[3]);
      *(ushort4*)(tb + row * 128 + jp + 8) = make_ushort4(he[4], he[5], he[6], he[7]);
    }
    __syncthreads();                   // wl reused by next half
  }
}

// ---------------- GEMM: 128x480 tile, BK=64, 8 waves (4m x 2n), split-K (R9 verbatim) --------
__global__ __launch_bounds__(512, 2) void hs_gemm(
    const float* __restrict__ x, const unsigned char* __restrict__ wt,
    float* __restrict__ partials, int ksplit, int tpc) {
  extern __shared__ __align__(16) unsigned char smem[];
  const int bid   = blockIdx.x;
  const int chunk = bid % ksplit;            // same-chunk blocks cluster on XCDs (wt L2 reuse)
  const int mtile = bid / ksplit;
  const int t0 = chunk * tpc;
  int t1 = t0 + tpc; if (t1 > NT) t1 = NT;
  const int m0 = mtile * BM;
  const int tid = threadIdx.x;
  const int lane = tid & 63, wid = tid >> 6;
  const int wm = wid >> 1, wn = wid & 1;     // wave tile: 32 rows x 240 cols
  const int jl  = (lane >> 4) * 16;          // frag k-offset bytes within a 64B k-half
  const int l15 = lane & 15;

  // A staging geometry: thread covers row tid>>2, 16 k-elems at (tid&3)*16
  const int arow = tid >> 2, c16 = tid & 3;
  const float* xr = x + (size_t)(m0 + arow) * KDIM + c16 * 16;

  f32x4 acc[2][15];
#pragma unroll
  for (int mf = 0; mf < 2; ++mf)
#pragma unroll
    for (int nf = 0; nf < 15; ++nf)
      acc[mf][nf] = f32x4{0.f, 0.f, 0.f, 0.f};

  auto stageB = [&](int kt, int buf) {   // 60 x 1KB wave-chunks, pre-swizzled in ws
    const unsigned char* src = wt + (size_t)kt * TILE_B + lane * 16;
    unsigned char* dstb = smem + buf * BUF_B;
#pragma unroll
    for (int c = 0; c < 8; ++c) {
      const int cc = wid + c * 8;
      if (cc < 60) {
        __builtin_amdgcn_global_load_lds(
            (const __attribute__((address_space(1))) unsigned int*)(src + cc * 1024),
            (__attribute__((address_space(3))) unsigned int*)(dstb + cc * 1024),
            16, 0, 0);
      }
    }
  };

  auto loadA = [&](int kt, f32x4& v0, f32x4& v1, f32x4& v2, f32x4& v3) {
    const int kb = kt * BK + c16 * 16;
    const float* p = xr + (size_t)kt * BK;
    if (kb + 16 <= KDIM) {
      __builtin_memcpy(&v0, p, 16);      __builtin_memcpy(&v1, p + 4, 16);
      __builtin_memcpy(&v2, p + 8, 16);  __builtin_memcpy(&v3, p + 12, 16);
    } else {                              // only the last K-tile takes this path
#pragma unroll
      for (int e = 0; e < 4; ++e) {
        v0[e] = (kb + e < KDIM)      ? p[e]      : 0.f;
        v1[e] = (kb + 4 + e < KDIM)  ? p[4 + e]  : 0.f;
        v2[e] = (kb + 8 + e < KDIM)  ? p[8 + e]  : 0.f;
        v3[e] = (kb + 12 + e < KDIM) ? p[12 + e] : 0.f;
      }
    }
  };

  auto writeA = [&](int buf, const f32x4& v0, const f32x4& v1,
                    const f32x4& v2, const f32x4& v3) {
    unsigned char* ab = smem + buf * BUF_B + TILE_B + arow * 128;
    unsigned short he[16];
#pragma unroll
    for (int e = 0; e < 4; ++e) {
      he[e]      = f2h(v0[e]);
      he[4 + e]  = f2h(v1[e]);
      he[8 + e]  = f2h(v2[e]);
      he[12 + e] = f2h(v3[e]);
    }
    const int s = swz8(arow);
    __builtin_memcpy(ab + ((c16 * 32) ^ s),      he,     16);   // ds_write_b128 x2
    __builtin_memcpy(ab + ((c16 * 32 + 16) ^ s), he + 8, 16);
  };

  auto compute = [&](int buf) {          // flat block: compiler pipelines ds_read/MFMA
    const unsigned char* bb = smem + buf * BUF_B;
    const unsigned char* ab = bb + TILE_B;
#pragma unroll
    for (int ks = 0; ks < 2; ++ks) {     // two K=32 sub-steps per 64-wide tile
      const int kbyte = ks * 64 + jl;
      f16x8 ah[2];
#pragma unroll
      for (int mf = 0; mf < 2; ++mf) {
        const int m = wm * 32 + mf * 16 + l15;
        ah[mf] = *(const f16x8*)(ab + m * 128 + (kbyte ^ swz8(m)));
      }
#pragma unroll
      for (int nf = 0; nf < 15; ++nf) {
        const int n = wn * 240 + nf * 16 + l15;
        const f16x8 bw = *(const f16x8*)(bb + n * 128 + (kbyte ^ swz8(n)));
        acc[0][nf] = __builtin_amdgcn_mfma_f32_16x16x32_f16(ah[0], bw, acc[0][nf], 0, 0, 0);
        acc[1][nf] = __builtin_amdgcn_mfma_f32_16x16x32_f16(ah[1], bw, acc[1][nf], 0, 0, 0);
      }
    }
  };

  if (t0 < t1) {
    f32x4 v0, v1, v2, v3;
    stageB(t0, 0);
    loadA(t0, v0, v1, v2, v3);
    writeA(0, v0, v1, v2, v3);          // implicit vmcnt wait on own loads
    __syncthreads();
    int buf = 0;
    for (int t = t0; t < t1; ++t) {
      const bool more = (t + 1 < t1);
      if (more) {                       // prefetch next tile before compute (2-phase)
        stageB(t + 1, buf ^ 1);
        loadA(t + 1, v0, v1, v2, v3);
      }
      compute(buf);
      if (more) writeA(buf ^ 1, v0, v1, v2, v3);
      __syncthreads();
      buf ^= 1;
    }
  }

  // epilogue: C/D frag map (m89): lane l, reg r -> row=(l>>4)*4+r, col=l&15
  float* pout = partials + ((size_t)chunk * BATCH + m0) * NPAD;
#pragma unroll
  for (int mf = 0; mf < 2; ++mf)
#pragma unroll
    for (int nf = 0; nf < 15; ++nf)
#pragma unroll
      for (int r = 0; r < 4; ++r) {
        const int row = wm * 32 + mf * 16 + (lane >> 4) * 4 + r;
        const int col = wn * 240 + nf * 16 + l15;
        pout[(size_t)row * NPAD + col] = acc[mf][nf][r];
      }
}

// ---------------- finish: reduce + bias + softmax x2 + float4 outer-product store -------------
__global__ __launch_bounds__(512) void hs_finish(
    const float* __restrict__ partials, const float* __restrict__ b0,
    const float* __restrict__ b1, float* __restrict__ out, int ksplit) {
  const int b = blockIdx.x;
  __shared__ float lg[NPAD];
  __shared__ float lrep[4 * 227];   // 4 copies of h1 @ stride 227 (227g mod 4 all distinct ->
                                    // 16-lane groups hit disjoint bank cosets: 2-way = free)
  __shared__ float red[4];          // {max0, 1/sum0, max1, 1/sum1}
  const int tid = threadIdx.x;
  if (tid < NPAD) {
    float v = 0.f;
    for (int c = 0; c < ksplit; ++c)
      v += partials[((size_t)c * BATCH + b) * NPAD + tid];
    v *= (1.0f / WSCALE);           // undo W pre-scale
    if (tid < LSZ) v += b0[tid];
    else if (tid >= HOFF && tid < HOFF + LSZ) v += b1[tid - HOFF];
    lg[tid] = v;
  }
  __syncthreads();
  const int wid = tid >> 6, lane = tid & 63;
  if (wid < 2) {                    // wave 0 -> head0, wave 1 -> head1
    const int base = wid * HOFF;
    float m = -1e30f;
    for (int i = lane; i < LSZ; i += 64) m = fmaxf(m, lg[base + i]);
#pragma unroll
    for (int s = 32; s; s >>= 1) m = fmaxf(m, __shfl_xor(m, s));
    float sum = 0.f;
    for (int i = lane; i < LSZ; i += 64) sum += __expf(lg[base + i] - m);
#pragma unroll
    for (int s = 32; s; s >>= 1) sum += __shfl_xor(sum, s);
    if (lane == 0) { red[wid * 2] = m; red[wid * 2 + 1] = 1.0f / sum; }
  }
  __syncthreads();
  if (tid < NPAD) {                 // own-index read-modify-write: no extra barrier needed
    const int h = (tid >= HOFF) ? 1 : 0;
    const int off = tid - (h ? HOFF : 0);
    float hv = 0.f;
    if (off < LSZ) hv = __expf(lg[tid] - red[2 * h]) * red[2 * h + 1];
    lg[tid] = hv;
  }
  __syncthreads();
  for (int u = tid; u < 4 * LSZ; u += 512) {   // replicate h1 into 4 rotated copies
    const int p = u / LSZ;
    const int j = u - LSZ * p;
    lrep[p * 227 + j] = lg[HOFF + j];
  }
  __syncthreads();
  const size_t ob = (size_t)b * KDIM;
  const int h4 = (int)((4 - (ob & 3)) & 3);    // head elems to align float4 body
  if (tid < h4) out[ob + tid] = lg[0] * lg[HOFF + tid];   // i = 0, j = tid (h4 <= 3)
  const float* rp = lrep + ((tid >> 4) & 3) * 227;        // per-16-lane-group copy
  const int nbody = (KDIM - h4) >> 2;
  for (int q = tid; q < nbody; q += 512) {
    const int f = h4 + q * 4;
    const int i = f / LSZ;          // compiler magic-mul
    const int j = f - i * LSZ;      // j in [0,225); wrap at most once across j..j+3
    const float h0a = lg[i];
    const float h0b = lg[i + 1];    // i+1 <= 224: valid h0 slot
    const int j1 = j + 1, j2 = j + 2, j3 = j + 3;
    float4 v;
    v.x = h0a * rp[j];
    v.y = (j1 < LSZ ? h0a : h0b) * rp[j1 < LSZ ? j1 : j1 - LSZ];
    v.z = (j2 < LSZ ? h0a : h0b) * rp[j2 < LSZ ? j2 : j2 - LSZ];
    v.w = (j3 < LSZ ? h0a : h0b) * rp[j3 < LSZ ? j3 : j3 - LSZ];
    *(float4*)(out + ob + f) = v;   // 16B-aligned: (ob + h4) % 4 == 0
  }
  const int be = h4 + nbody * 4;    // tail: < 4 elems
  if (tid < KDIM - be) {
    const int f = be + tid;
    const int i = f / LSZ;
    const int j = f - i * LSZ;
    out[ob + f] = lg[i] * lg[HOFF + j];
  }
}

extern "C" void kernel_launch(void* const* d_in, const int* in_sizes, int n_in,
                              void* d_out, int out_size, void* d_ws, size_t ws_size,
                              hipStream_t stream) {
  (void)in_sizes; (void)n_in; (void)out_size;
  const float* x  = (const float*)d_in[0];
  const float* W0 = (const float*)d_in[1];
  const float* W1 = (const float*)d_in[2];
  const float* b0 = (const float*)d_in[3];
  const float* b1 = (const float*)d_in[4];
  float* out = (float*)d_out;
  unsigned char* ws = (unsigned char*)d_ws;

  const size_t WT_BYTES  = (size_t)NT * TILE_B;            // 48.3 MB
  const size_t PER_CHUNK = (size_t)BATCH * NPAD * sizeof(float);
  int ksplit = 16;
  if (ws_size > WT_BYTES) {
    const int kmax = (int)((ws_size - WT_BYTES) / PER_CHUNK);
    if (ksplit > kmax) ksplit = kmax;
  } else {
    ksplit = 1;
  }
  if (ksplit < 1) ksplit = 1;
  float* partials = (float*)(ws + WT_BYTES);
  const int tpc = (NT + ksplit - 1) / ksplit;

  hs_prep<<<dim3(NT), dim3(512), 0, stream>>>(W0, W1, ws);
  hipFuncSetAttribute((const void*)hs_gemm,
                      hipFuncAttributeMaxDynamicSharedMemorySize, LDS_TOT);
  hs_gemm<<<dim3(16 * ksplit), dim3(512), LDS_TOT, stream>>>(x, ws, partials, ksplit, tpc);
  hs_finish<<<dim3(BATCH), dim3(512), 0, stream>>>(partials, b0, b1, out, ksplit);
}

// Round 12
// 361.129 us; speedup vs baseline: 1.0882x; 1.0882x over previous
//
#include <hip/hip_runtime.h>
#include <stdint.h>
#include <math.h>

// HierarchicalSoftmax: out[b, i*225+j] = softmax(x@W0+b0)[b,i] * softmax(x@W1+b1)[b,j], f<50257
//
// Pipeline (R12 ablation: gemm + prep = R9 verbatim (best measured, 324us).
//           finish = R11's float4-store version. Attributes R11's +69us regression.)
//  1) hs_prep : W0,W1 fp32 [K][225] -> ws: per-K-tile images of W^T [480][128B] fp16 (x1024),
//               row-XOR-swizzled (16B-block ^= row&7).
//  2) hs_gemm : logits*1024 = (fp16)x @ (fp16)([W0|W1]*1024), fp32 acc, split-K partials.
//  3) hs_finish: reduce partials * 2^-10 + bias, per-head softmax, outer-product float4 store
//               (4 rotated h1 copies @ stride 227 in LDS -> group-disjoint bank cosets).

#define BATCH   2048
#define KDIM    50257
#define LSZ     225
#define HOFF    240        // head1 column offset in padded logits
#define NPAD    480        // padded N: [0,225) = head0, [240,465) = head1, rest zero
#define BK      64
#define BM      128
#define NT      786        // ceil(50257/64)
#define TILE_B  61440      // B tile bytes: 480 rows * 128B (fp16)
#define A_BYTES 16384      // A tile bytes: 128 rows * 128B (fp16)
#define BUF_B   77824      // TILE_B + A_BYTES
#define LDS_TOT 155648     // 2 * BUF_B (double buffer)
#define WSCALE  1024.0f    // W pre-scale: keeps fp16 weights out of denormal range

typedef __attribute__((ext_vector_type(8))) _Float16 f16x8;
typedef __attribute__((ext_vector_type(4))) float    f32x4;

__device__ __forceinline__ unsigned short f2h(float f) {    // fp32 -> fp16 bits (RNE)
  return __builtin_bit_cast(unsigned short, (_Float16)f);
}
// 128B-row swizzle: XOR 16B-block index by (row&7) -> 16-row frag reads = 2-way (free)
__device__ __forceinline__ int swz8(int r) { return (r & 7) << 4; }

// ---------------- prep: build swizzled, tiled fp16 W^T (scaled x1024) — R9 verbatim ----------
__global__ __launch_bounds__(512) void hs_prep(const float* __restrict__ W0,
                                               const float* __restrict__ W1,
                                               unsigned char* __restrict__ wt) {
  const int kt = blockIdx.x;           // one K-tile (64 k's) per block
  const int k0 = kt * BK;
  unsigned char* tb = wt + (size_t)kt * TILE_B;
  for (int idx = threadIdx.x; idx < NPAD * 16; idx += 512) {
    const int n = idx >> 4, c4 = idx & 15;      // row n, 4-elem (8B) group c4
    const float* src = nullptr;
    if (n < HOFF) { if (n < LSZ) src = W0 + n; }
    else          { if (n - HOFF < LSZ) src = W1 + (n - HOFF); }
    unsigned short he[4];
#pragma unroll
    for (int e = 0; e < 4; ++e) {
      const int k = k0 + c4 * 4 + e;
      float v = (src != nullptr && k < KDIM) ? src[(size_t)k * LSZ] * WSCALE : 0.0f;
      he[e] = f2h(v);
    }
    const int jp = (c4 * 8) ^ swz8(n);          // XOR permutes 16B blocks, keeps 8B phase
    *(ushort4*)(tb + n * 128 + jp) = make_ushort4(he[0], he[1], he[2], he[3]);
  }
}

// ---------------- GEMM: 128x480 tile, BK=64, 8 waves (4m x 2n), split-K (R9 verbatim) --------
__global__ __launch_bounds__(512, 2) void hs_gemm(
    const float* __restrict__ x, const unsigned char* __restrict__ wt,
    float* __restrict__ partials, int ksplit, int tpc) {
  extern __shared__ __align__(16) unsigned char smem[];
  const int bid   = blockIdx.x;
  const int chunk = bid % ksplit;            // same-chunk blocks cluster on XCDs (wt L2 reuse)
  const int mtile = bid / ksplit;
  const int t0 = chunk * tpc;
  int t1 = t0 + tpc; if (t1 > NT) t1 = NT;
  const int m0 = mtile * BM;
  const int tid = threadIdx.x;
  const int lane = tid & 63, wid = tid >> 6;
  const int wm = wid >> 1, wn = wid & 1;     // wave tile: 32 rows x 240 cols
  const int jl  = (lane >> 4) * 16;          // frag k-offset bytes within a 64B k-half
  const int l15 = lane & 15;

  // A staging geometry: thread covers row tid>>2, 16 k-elems at (tid&3)*16
  const int arow = tid >> 2, c16 = tid & 3;
  const float* xr = x + (size_t)(m0 + arow) * KDIM + c16 * 16;

  f32x4 acc[2][15];
#pragma unroll
  for (int mf = 0; mf < 2; ++mf)
#pragma unroll
    for (int nf = 0; nf < 15; ++nf)
      acc[mf][nf] = f32x4{0.f, 0.f, 0.f, 0.f};

  auto stageB = [&](int kt, int buf) {   // 60 x 1KB wave-chunks, pre-swizzled in ws
    const unsigned char* src = wt + (size_t)kt * TILE_B + lane * 16;
    unsigned char* dstb = smem + buf * BUF_B;
#pragma unroll
    for (int c = 0; c < 8; ++c) {
      const int cc = wid + c * 8;
      if (cc < 60) {
        __builtin_amdgcn_global_load_lds(
            (const __attribute__((address_space(1))) unsigned int*)(src + cc * 1024),
            (__attribute__((address_space(3))) unsigned int*)(dstb + cc * 1024),
            16, 0, 0);
      }
    }
  };

  auto loadA = [&](int kt, f32x4& v0, f32x4& v1, f32x4& v2, f32x4& v3) {
    const int kb = kt * BK + c16 * 16;
    const float* p = xr + (size_t)kt * BK;
    if (kb + 16 <= KDIM) {
      __builtin_memcpy(&v0, p, 16);      __builtin_memcpy(&v1, p + 4, 16);
      __builtin_memcpy(&v2, p + 8, 16);  __builtin_memcpy(&v3, p + 12, 16);
    } else {                              // only the last K-tile takes this path
#pragma unroll
      for (int e = 0; e < 4; ++e) {
        v0[e] = (kb + e < KDIM)      ? p[e]      : 0.f;
        v1[e] = (kb + 4 + e < KDIM)  ? p[4 + e]  : 0.f;
        v2[e] = (kb + 8 + e < KDIM)  ? p[8 + e]  : 0.f;
        v3[e] = (kb + 12 + e < KDIM) ? p[12 + e] : 0.f;
      }
    }
  };

  auto writeA = [&](int buf, const f32x4& v0, const f32x4& v1,
                    const f32x4& v2, const f32x4& v3) {
    unsigned char* ab = smem + buf * BUF_B + TILE_B + arow * 128;
    unsigned short he[16];
#pragma unroll
    for (int e = 0; e < 4; ++e) {
      he[e]      = f2h(v0[e]);
      he[4 + e]  = f2h(v1[e]);
      he[8 + e]  = f2h(v2[e]);
      he[12 + e] = f2h(v3[e]);
    }
    const int s = swz8(arow);
    __builtin_memcpy(ab + ((c16 * 32) ^ s),      he,     16);   // ds_write_b128 x2
    __builtin_memcpy(ab + ((c16 * 32 + 16) ^ s), he + 8, 16);
  };

  auto compute = [&](int buf) {          // flat block: compiler pipelines ds_read/MFMA
    const unsigned char* bb = smem + buf * BUF_B;
    const unsigned char* ab = bb + TILE_B;
#pragma unroll
    for (int ks = 0; ks < 2; ++ks) {     // two K=32 sub-steps per 64-wide tile
      const int kbyte = ks * 64 + jl;
      f16x8 ah[2];
#pragma unroll
      for (int mf = 0; mf < 2; ++mf) {
        const int m = wm * 32 + mf * 16 + l15;
        ah[mf] = *(const f16x8*)(ab + m * 128 + (kbyte ^ swz8(m)));
      }
#pragma unroll
      for (int nf = 0; nf < 15; ++nf) {
        const int n = wn * 240 + nf * 16 + l15;
        const f16x8 bw = *(const f16x8*)(bb + n * 128 + (kbyte ^ swz8(n)));
        acc[0][nf] = __builtin_amdgcn_mfma_f32_16x16x32_f16(ah[0], bw, acc[0][nf], 0, 0, 0);
        acc[1][nf] = __builtin_amdgcn_mfma_f32_16x16x32_f16(ah[1], bw, acc[1][nf], 0, 0, 0);
      }
    }
  };

  if (t0 < t1) {
    f32x4 v0, v1, v2, v3;
    stageB(t0, 0);
    loadA(t0, v0, v1, v2, v3);
    writeA(0, v0, v1, v2, v3);          // implicit vmcnt wait on own loads
    __syncthreads();
    int buf = 0;
    for (int t = t0; t < t1; ++t) {
      const bool more = (t + 1 < t1);
      if (more) {                       // prefetch next tile before compute (2-phase)
        stageB(t + 1, buf ^ 1);
        loadA(t + 1, v0, v1, v2, v3);
      }
      compute(buf);
      if (more) writeA(buf ^ 1, v0, v1, v2, v3);
      __syncthreads();
      buf ^= 1;
    }
  }

  // epilogue: C/D frag map (m89): lane l, reg r -> row=(l>>4)*4+r, col=l&15
  float* pout = partials + ((size_t)chunk * BATCH + m0) * NPAD;
#pragma unroll
  for (int mf = 0; mf < 2; ++mf)
#pragma unroll
    for (int nf = 0; nf < 15; ++nf)
#pragma unroll
      for (int r = 0; r < 4; ++r) {
        const int row = wm * 32 + mf * 16 + (lane >> 4) * 4 + r;
        const int col = wn * 240 + nf * 16 + l15;
        pout[(size_t)row * NPAD + col] = acc[mf][nf][r];
      }
}

// ---------------- finish: reduce + bias + softmax x2 + float4 outer-product store -------------
__global__ __launch_bounds__(512) void hs_finish(
    const float* __restrict__ partials, const float* __restrict__ b0,
    const float* __restrict__ b1, float* __restrict__ out, int ksplit) {
  const int b = blockIdx.x;
  __shared__ float lg[NPAD];
  __shared__ float lrep[4 * 227];   // 4 copies of h1 @ stride 227 (227g mod 4 all distinct ->
                                    // 16-lane groups hit disjoint bank cosets: 2-way = free)
  __shared__ float red[4];          // {max0, 1/sum0, max1, 1/sum1}
  const int tid = threadIdx.x;
  if (tid < NPAD) {
    float v = 0.f;
    for (int c = 0; c < ksplit; ++c)
      v += partials[((size_t)c * BATCH + b) * NPAD + tid];
    v *= (1.0f / WSCALE);           // undo W pre-scale
    if (tid < LSZ) v += b0[tid];
    else if (tid >= HOFF && tid < HOFF + LSZ) v += b1[tid - HOFF];
    lg[tid] = v;
  }
  __syncthreads();
  const int wid = tid >> 6, lane = tid & 63;
  if (wid < 2) {                    // wave 0 -> head0, wave 1 -> head1
    const int base = wid * HOFF;
    float m = -1e30f;
    for (int i = lane; i < LSZ; i += 64) m = fmaxf(m, lg[base + i]);
#pragma unroll
    for (int s = 32; s; s >>= 1) m = fmaxf(m, __shfl_xor(m, s));
    float sum = 0.f;
    for (int i = lane; i < LSZ; i += 64) sum += __expf(lg[base + i] - m);
#pragma unroll
    for (int s = 32; s; s >>= 1) sum += __shfl_xor(sum, s);
    if (lane == 0) { red[wid * 2] = m; red[wid * 2 + 1] = 1.0f / sum; }
  }
  __syncthreads();
  if (tid < NPAD) {                 // own-index read-modify-write: no extra barrier needed
    const int h = (tid >= HOFF) ? 1 : 0;
    const int off = tid - (h ? HOFF : 0);
    float hv = 0.f;
    if (off < LSZ) hv = __expf(lg[tid] - red[2 * h]) * red[2 * h + 1];
    lg[tid] = hv;
  }
  __syncthreads();
  for (int u = tid; u < 4 * LSZ; u += 512) {   // replicate h1 into 4 rotated copies
    const int p = u / LSZ;
    const int j = u - LSZ * p;
    lrep[p * 227 + j] = lg[HOFF + j];
  }
  __syncthreads();
  const size_t ob = (size_t)b * KDIM;
  const int h4 = (int)((4 - (ob & 3)) & 3);    // head elems to align float4 body
  if (tid < h4) out[ob + tid] = lg[0] * lg[HOFF + tid];   // i = 0, j = tid (h4 <= 3)
  const float* rp = lrep + ((tid >> 4) & 3) * 227;        // per-16-lane-group copy
  const int nbody = (KDIM - h4) >> 2;
  for (int q = tid; q < nbody; q += 512) {
    const int f = h4 + q * 4;
    const int i = f / LSZ;          // compiler magic-mul
    const int j = f - i * LSZ;      // j in [0,225); wrap at most once across j..j+3
    const float h0a = lg[i];
    const float h0b = lg[i + 1];    // i+1 <= 224: valid h0 slot
    const int j1 = j + 1, j2 = j + 2, j3 = j + 3;
    float4 v;
    v.x = h0a * rp[j];
    v.y = (j1 < LSZ ? h0a : h0b) * rp[j1 < LSZ ? j1 : j1 - LSZ];
    v.z = (j2 < LSZ ? h0a : h0b) * rp[j2 < LSZ ? j2 : j2 - LSZ];
    v.w = (j3 < LSZ ? h0a : h0b) * rp[j3 < LSZ ? j3 : j3 - LSZ];
    *(float4*)(out + ob + f) = v;   // 16B-aligned: (ob + h4) % 4 == 0
  }
  const int be = h4 + nbody * 4;    // tail: < 4 elems
  if (tid < KDIM - be) {
    const int f = be + tid;
    const int i = f / LSZ;
    const int j = f - i * LSZ;
    out[ob + f] = lg[i] * lg[HOFF + j];
  }
}

extern "C" void kernel_launch(void* const* d_in, const int* in_sizes, int n_in,
                              void* d_out, int out_size, void* d_ws, size_t ws_size,
                              hipStream_t stream) {
  (void)in_sizes; (void)n_in; (void)out_size;
  const float* x  = (const float*)d_in[0];
  const float* W0 = (const float*)d_in[1];
  const float* W1 = (const float*)d_in[2];
  const float* b0 = (const float*)d_in[3];
  const float* b1 = (const float*)d_in[4];
  float* out = (float*)d_out;
  unsigned char* ws = (unsigned char*)d_ws;

  const size_t WT_BYTES  = (size_t)NT * TILE_B;            // 48.3 MB
  const size_t PER_CHUNK = (size_t)BATCH * NPAD * sizeof(float);
  int ksplit = 16;
  if (ws_size > WT_BYTES) {
    const int kmax = (int)((ws_size - WT_BYTES) / PER_CHUNK);
    if (ksplit > kmax) ksplit = kmax;
  } else {
    ksplit = 1;
  }
  if (ksplit < 1) ksplit = 1;
  float* partials = (float*)(ws + WT_BYTES);
  const int tpc = (NT + ksplit - 1) / ksplit;

  hs_prep<<<dim3(NT), dim3(512), 0, stream>>>(W0, W1, ws);
  hipFuncSetAttribute((const void*)hs_gemm,
                      hipFuncAttributeMaxDynamicSharedMemorySize, LDS_TOT);
  hs_gemm<<<dim3(16 * ksplit), dim3(512), LDS_TOT, stream>>>(x, ws, partials, ksplit, tpc);
  hs_finish<<<dim3(BATCH), dim3(512), 0, stream>>>(partials, b0, b1, out, ksplit);
}

// Round 13
// 342.380 us; speedup vs baseline: 1.1478x; 1.0548x over previous
//
#include <hip/hip_runtime.h>
#include <stdint.h>
#include <math.h>

// HierarchicalSoftmax: out[b, i*225+j] = softmax(x@W0+b0)[b,i] * softmax(x@W1+b1)[b,j], f<50257
//
// Pipeline (R13: 3-buffer LDS rotation + counted vmcnt. R9's loop had a structural flaw:
//           writeA needed loadA data issued AFTER the stage DMAs -> implicit vmcnt(0) drain
//           every iteration. Now: loadA(t+2)+stage(t+2) issued before compute(t); post-compute
//           vmcnt(4) leaves stage(t+2)'s 4 DMAs/wave in flight across the barrier (T4).
//           BK=32, 8 waves 4m x 2n, acc[2][15], single-term fp16 (R5 geometry)):
//  1) hs_prep : W0,W1 -> ws: per-K-tile images of W^T [480][64B] fp16 (x1024), swzr-swizzled.
//  2) hs_gemm : logits*1024 = (fp16)x @ (fp16)W', fp32 acc, split-K partials.
//  3) hs_finish: reduce partials * 2^-10 + bias, per-head softmax, outer-product store (R9).

#define BATCH   2048
#define KDIM    50257
#define LSZ     225
#define HOFF    240        // head1 column offset in padded logits
#define NPAD    480        // padded N: [0,225) = head0, [240,465) = head1, rest zero
#define BK      32
#define BM      128
#define NT      1571       // ceil(50257/32)
#define TILE_B  30720      // B tile bytes: 480 rows * 64B (fp16)
#define A_BYTES 8192       // A tile bytes: 128 rows * 64B (fp16)
#define BUF_B   38912      // TILE_B + A_BYTES
#define LDS_TOT 117760     // 3 * BUF_B + 1KB dead zone (uniform 4-DMA staging per wave)
#define WSCALE  1024.0f    // W pre-scale: keeps fp16 weights out of denormal range

typedef __attribute__((ext_vector_type(8))) _Float16 f16x8;
typedef __attribute__((ext_vector_type(4))) float    f32x4;

__device__ __forceinline__ unsigned short f2h(float f) {    // fp32 -> fp16 bits (RNE)
  return __builtin_bit_cast(unsigned short, (_Float16)f);
}
// XOR swizzle: flip byte-offset bits 4-5 by row bits 1-2 -> frag ds_read_b128 is 2-way (free)
__device__ __forceinline__ int swzr(int r) { return ((r >> 1) & 3) << 4; }

#define ASM_VMCNT0() asm volatile("s_waitcnt vmcnt(0)" ::: "memory")
#define ASM_VMCNT4() asm volatile("s_waitcnt vmcnt(4)" ::: "memory")
#define ASM_LGKM0()  asm volatile("s_waitcnt lgkmcnt(0)" ::: "memory")

// ---------------- prep: build swizzled, tiled fp16 W^T (scaled x1024) — R5 verbatim ----------
__global__ __launch_bounds__(512) void hs_prep(const float* __restrict__ W0,
                                               const float* __restrict__ W1,
                                               unsigned char* __restrict__ wt) {
  const int kt = blockIdx.x;           // one K-tile per block
  const int k0 = kt * BK;
  unsigned char* tb = wt + (size_t)kt * TILE_B;
  for (int idx = threadIdx.x; idx < NPAD * 8; idx += 512) {
    const int n = idx >> 3, c4 = idx & 7;       // row n, 4-elem group c4
    const float* src = nullptr;
    if (n < HOFF) { if (n < LSZ) src = W0 + n; }
    else          { if (n - HOFF < LSZ) src = W1 + (n - HOFF); }
    unsigned short he[4];
#pragma unroll
    for (int e = 0; e < 4; ++e) {
      const int k = k0 + c4 * 4 + e;
      float v = (src != nullptr && k < KDIM) ? src[(size_t)k * LSZ] * WSCALE : 0.0f;
      he[e] = f2h(v);
    }
    const int jp = (c4 * 8) ^ swzr(n);
    *(ushort4*)(tb + n * 64 + jp) = make_ushort4(he[0], he[1], he[2], he[3]);
  }
}

// ---------------- GEMM: 128x480 tile, BK=32, 8 waves (4m x 2n), split-K, 3-buffer ------------
__global__ __launch_bounds__(512, 2) void hs_gemm(
    const float* __restrict__ x, const unsigned char* __restrict__ wt,
    float* __restrict__ partials, int ksplit, int tpc) {
  extern __shared__ __align__(16) unsigned char smem[];
  const int bid   = blockIdx.x;
  const int chunk = bid % ksplit;            // same-chunk blocks cluster on XCDs (wt L2 reuse)
  const int mtile = bid / ksplit;
  const int t0 = chunk * tpc;
  int t1 = t0 + tpc; if (t1 > NT) t1 = NT;
  const int m0 = mtile * BM;
  const int tid = threadIdx.x;
  const int lane = tid & 63, wid = tid >> 6;
  const int wm = wid >> 1, wn = wid & 1;     // wave tile: 32 rows x 240 cols
  const int jl  = (lane >> 4) * 16;          // frag k-offset bytes (8 f16)
  const int l15 = lane & 15;

  // A staging geometry: thread covers rows arow0 and arow0+64, 4 k-elems each
  const int arow0 = tid >> 3, c4 = tid & 7;
  const int arow1 = arow0 + 64;
  const float* xr0 = x + (size_t)(m0 + arow0) * KDIM + c4 * 4;
  const float* xr1 = xr0 + (size_t)64 * KDIM;
  const int aoff0 = arow0 * 64 + ((c4 * 8) ^ swzr(arow0));
  const int aoff1 = arow1 * 64 + ((c4 * 8) ^ swzr(arow1));

  f32x4 acc[2][15];
#pragma unroll
  for (int mf = 0; mf < 2; ++mf)
#pragma unroll
    for (int nf = 0; nf < 15; ++nf)
      acc[mf][nf] = f32x4{0.f, 0.f, 0.f, 0.f};

  // uniform 4-DMA burst per wave: 30 real 1KB chunks + 2 dead (cc>=30) -> vmcnt count = 4/wave
  auto stageB = [&](int kt, int buf) {
    const unsigned char* src = wt + (size_t)kt * TILE_B + lane * 16;
    unsigned char* dstb = smem + buf * BUF_B;
#pragma unroll
    for (int c = 0; c < 4; ++c) {
      const int cc = wid + c * 8;
      const unsigned char* s = src + (cc < 30 ? cc : 0) * 1024;
      unsigned char* d = (cc < 30) ? (dstb + cc * 1024) : (smem + 3 * BUF_B);
      __builtin_amdgcn_global_load_lds(
          (const __attribute__((address_space(1))) unsigned int*)s,
          (__attribute__((address_space(3))) unsigned int*)d, 16, 0, 0);
    }
  };

  auto loadA = [&](int kt, f32x4& v0, f32x4& v1) {
    const int kb = kt * BK + c4 * 4;
    const float* p0 = xr0 + (size_t)kt * BK;
    const float* p1 = xr1 + (size_t)kt * BK;
    if (kb + 4 <= KDIM) {
      __builtin_memcpy(&v0, p0, 16);
      __builtin_memcpy(&v1, p1, 16);
    } else {
#pragma unroll
      for (int e = 0; e < 4; ++e) {
        v0[e] = (kb + e < KDIM) ? p0[e] : 0.f;
        v1[e] = (kb + e < KDIM) ? p1[e] : 0.f;
      }
    }
  };

  auto writeA = [&](int buf, const f32x4& v0, const f32x4& v1) {
    unsigned char* ab = smem + buf * BUF_B + TILE_B;
    unsigned short h0e[4], h1e[4];
#pragma unroll
    for (int e = 0; e < 4; ++e) {
      h0e[e] = f2h(v0[e]);
      h1e[e] = f2h(v1[e]);
    }
    *(ushort4*)(ab + aoff0) = make_ushort4(h0e[0], h0e[1], h0e[2], h0e[3]);
    *(ushort4*)(ab + aoff1) = make_ushort4(h1e[0], h1e[1], h1e[2], h1e[3]);
  };

  auto compute = [&](int buf) {          // flat block: compiler pipelines ds_read/MFMA
    const unsigned char* bb = smem + buf * BUF_B;
    const unsigned char* ab = bb + TILE_B;
    f16x8 ah[2];
#pragma unroll
    for (int mf = 0; mf < 2; ++mf) {
      const int m = wm * 32 + mf * 16 + l15;
      const int off = m * 64 + (jl ^ swzr(m));
      ah[mf] = *(const f16x8*)(ab + off);
    }
#pragma unroll
    for (int nf = 0; nf < 15; ++nf) {
      const int n = wn * 240 + nf * 16 + l15;
      const int off = n * 64 + (jl ^ swzr(n));
      const f16x8 bw = *(const f16x8*)(bb + off);
      acc[0][nf] = __builtin_amdgcn_mfma_f32_16x16x32_f16(ah[0], bw, acc[0][nf], 0, 0, 0);
      acc[1][nf] = __builtin_amdgcn_mfma_f32_16x16x32_f16(ah[1], bw, acc[1][nf], 0, 0, 0);
    }
  };

  if (t0 < t1) {
    f32x4 v0, v1;
    // prologue: tile t0 fully staged + drained; tile t0+1 A written, B-DMA left in flight
    stageB(t0, 0);
    loadA(t0, v0, v1);
    ASM_VMCNT0();
    writeA(0, v0, v1);
    if (t1 - t0 >= 2) {
      loadA(t0 + 1, v0, v1);
      __builtin_amdgcn_sched_barrier(0);   // pin issue order: loadA before stage DMAs
      stageB(t0 + 1, 1);
      ASM_VMCNT4();                        // drains loadA(t0+1); stage(t0+1) stays in flight
      writeA(1, v0, v1);
    }
    ASM_LGKM0();
    __builtin_amdgcn_s_barrier();

    int rb = 0;                            // buffer holding tile t
    for (int t = t0; t < t1; ++t) {
      const int bw2 = (rb >= 1) ? rb - 1 : rb + 2;   // (rb+2)%3: buffer for tile t+2
      const bool pf = (t + 2 < t1);
      if (pf) {
        loadA(t + 2, v0, v1);
        __builtin_amdgcn_sched_barrier(0); // pin issue order: loadA before stage DMAs
        stageB(t + 2, bw2);
      }
      compute(rb);                         // entry state: stage(t)+A(t) already visible
      if (t + 1 < t1) {
        if (pf) {
          ASM_VMCNT4();                    // drains stage(t+1)+loadA(t+2); keeps stage(t+2)
          writeA(bw2, v0, v1);
        } else {
          ASM_VMCNT0();                    // tail: drain remaining stage(t+1)
        }
        ASM_LGKM0();
        __builtin_amdgcn_s_barrier();
      }
      rb = (rb == 2) ? 0 : rb + 1;
    }
  }

  // epilogue: C/D frag map (m89): lane l, reg r -> row=(l>>4)*4+r, col=l&15
  float* pout = partials + ((size_t)chunk * BATCH + m0) * NPAD;
#pragma unroll
  for (int mf = 0; mf < 2; ++mf)
#pragma unroll
    for (int nf = 0; nf < 15; ++nf)
#pragma unroll
      for (int r = 0; r < 4; ++r) {
        const int row = wm * 32 + mf * 16 + (lane >> 4) * 4 + r;
        const int col = wn * 240 + nf * 16 + l15;
        pout[(size_t)row * NPAD + col] = acc[mf][nf][r];
      }
}

// ---------------- finish: reduce + bias + softmax x2 + outer-product store (R9 verbatim) ------
__global__ __launch_bounds__(512) void hs_finish(
    const float* __restrict__ partials, const float* __restrict__ b0,
    const float* __restrict__ b1, float* __restrict__ out, int ksplit) {
  const int b = blockIdx.x;
  __shared__ float lg[NPAD];
  __shared__ float red[4];          // {max0, 1/sum0, max1, 1/sum1}
  const int tid = threadIdx.x;
  if (tid < NPAD) {
    float v = 0.f;
    for (int c = 0; c < ksplit; ++c)
      v += partials[((size_t)c * BATCH + b) * NPAD + tid];
    v *= (1.0f / WSCALE);           // undo W pre-scale
    if (tid < LSZ) v += b0[tid];
    else if (tid >= HOFF && tid < HOFF + LSZ) v += b1[tid - HOFF];
    lg[tid] = v;
  }
  __syncthreads();
  const int wid = tid >> 6, lane = tid & 63;
  if (wid < 2) {                    // wave 0 -> head0, wave 1 -> head1
    const int base = wid * HOFF;
    float m = -1e30f;
    for (int i = lane; i < LSZ; i += 64) m = fmaxf(m, lg[base + i]);
#pragma unroll
    for (int s = 32; s; s >>= 1) m = fmaxf(m, __shfl_xor(m, s));
    float sum = 0.f;
    for (int i = lane; i < LSZ; i += 64) sum += __expf(lg[base + i] - m);
#pragma unroll
    for (int s = 32; s; s >>= 1) sum += __shfl_xor(sum, s);
    if (lane == 0) { red[wid * 2] = m; red[wid * 2 + 1] = 1.0f / sum; }
  }
  __syncthreads();
  if (tid < NPAD) {                 // own-index read-modify-write: no extra barrier needed
    const int h = (tid >= HOFF) ? 1 : 0;
    const int off = tid - (h ? HOFF : 0);
    float hv = 0.f;
    if (off < LSZ) hv = __expf(lg[tid] - red[2 * h]) * red[2 * h + 1];
    lg[tid] = hv;
  }
  __syncthreads();
  const size_t ob = (size_t)b * KDIM;
  for (int f = tid; f < KDIM; f += 512) {
    const int i = f / LSZ;          // compiler magic-mul; stride-1 LDS reads (conflict-free)
    const int j = f - i * LSZ;
    out[ob + f] = lg[i] * lg[HOFF + j];
  }
}

extern "C" void kernel_launch(void* const* d_in, const int* in_sizes, int n_in,
                              void* d_out, int out_size, void* d_ws, size_t ws_size,
                              hipStream_t stream) {
  (void)in_sizes; (void)n_in; (void)out_size;
  const float* x  = (const float*)d_in[0];
  const float* W0 = (const float*)d_in[1];
  const float* W1 = (const float*)d_in[2];
  const float* b0 = (const float*)d_in[3];
  const float* b1 = (const float*)d_in[4];
  float* out = (float*)d_out;
  unsigned char* ws = (unsigned char*)d_ws;

  const size_t WT_BYTES  = (size_t)NT * TILE_B;            // 48.3 MB
  const size_t PER_CHUNK = (size_t)BATCH * NPAD * sizeof(float);
  int ksplit = 16;
  if (ws_size > WT_BYTES) {
    const int kmax = (int)((ws_size - WT_BYTES) / PER_CHUNK);
    if (ksplit > kmax) ksplit = kmax;
  } else {
    ksplit = 1;
  }
  if (ksplit < 1) ksplit = 1;
  float* partials = (float*)(ws + WT_BYTES);
  const int tpc = (NT + ksplit - 1) / ksplit;

  hs_prep<<<dim3(NT), dim3(512), 0, stream>>>(W0, W1, ws);
  hipFuncSetAttribute((const void*)hs_gemm,
                      hipFuncAttributeMaxDynamicSharedMemorySize, LDS_TOT);
  hs_gemm<<<dim3(16 * ksplit), dim3(512), LDS_TOT, stream>>>(x, ws, partials, ksplit, tpc);
  hs_finish<<<dim3(BATCH), dim3(512), 0, stream>>>(partials, b0, b1, out, ksplit);
}

// Round 14
// 323.166 us; speedup vs baseline: 1.2160x; 1.0595x over previous
//
#include <hip/hip_runtime.h>
#include <stdint.h>
#include <math.h>

// HierarchicalSoftmax: out[b, i*225+j] = softmax(x@W0+b0)[b,i] * softmax(x@W1+b1)[b,j], f<50257
//
// FINAL (R14 = R9 verbatim, best measured 324.3us over 13 experimental rounds):
//  1) hs_prep : W0,W1 fp32 [K][225] -> ws: per-K-tile images of W^T [480][128B] fp16 (x1024),
//               row-XOR-swizzled (16B-block ^= row&7) for linear global_load_lds staging +
//               conflict-free ds_read_b128 frags.
//  2) hs_gemm : logits*1024 = (fp16)x @ (fp16)([W0|W1]*1024), fp32 acc, split-K partials.
//               BK=64, BM=128, 8 waves (4m x 2n), acc[2][15] -> AGPRs, 2-phase double buffer.
//  3) hs_finish: reduce partials * 2^-10 + bias, per-head softmax, fused outer-product store.
//
// Numerics: single-term fp16 (x RNE + W RNE, W prescaled x1024 to dodge denormals):
//           absmax 2.44e-4 vs 1.47e-3 threshold (6x margin). Verified bit-stable R9-R13.

#define BATCH   2048
#define KDIM    50257
#define LSZ     225
#define HOFF    240        // head1 column offset in padded logits
#define NPAD    480        // padded N: [0,225) = head0, [240,465) = head1, rest zero
#define BK      64
#define BM      128
#define NT      786        // ceil(50257/64)
#define TILE_B  61440      // B tile bytes: 480 rows * 128B (fp16)
#define A_BYTES 16384      // A tile bytes: 128 rows * 128B (fp16)
#define BUF_B   77824      // TILE_B + A_BYTES
#define LDS_TOT 155648     // 2 * BUF_B (double buffer), fits 160KB
#define WSCALE  1024.0f    // W pre-scale: keeps fp16 weights out of denormal range

typedef __attribute__((ext_vector_type(8))) _Float16 f16x8;
typedef __attribute__((ext_vector_type(4))) float    f32x4;

__device__ __forceinline__ unsigned short f2h(float f) {    // fp32 -> fp16 bits (RNE)
  return __builtin_bit_cast(unsigned short, (_Float16)f);
}
// 128B-row swizzle: XOR 16B-block index by (row&7) -> 16-row frag reads = 2-way (free)
__device__ __forceinline__ int swz8(int r) { return (r & 7) << 4; }

// ---------------- prep: build swizzled, tiled fp16 W^T (scaled x1024) ----------------
__global__ __launch_bounds__(512) void hs_prep(const float* __restrict__ W0,
                                               const float* __restrict__ W1,
                                               unsigned char* __restrict__ wt) {
  const int kt = blockIdx.x;           // one K-tile (64 k's) per block
  const int k0 = kt * BK;
  unsigned char* tb = wt + (size_t)kt * TILE_B;
  for (int idx = threadIdx.x; idx < NPAD * 16; idx += 512) {
    const int n = idx >> 4, c4 = idx & 15;      // row n, 4-elem (8B) group c4
    const float* src = nullptr;
    if (n < HOFF) { if (n < LSZ) src = W0 + n; }
    else          { if (n - HOFF < LSZ) src = W1 + (n - HOFF); }
    unsigned short he[4];
#pragma unroll
    for (int e = 0; e < 4; ++e) {
      const int k = k0 + c4 * 4 + e;
      float v = (src != nullptr && k < KDIM) ? src[(size_t)k * LSZ] * WSCALE : 0.0f;
      he[e] = f2h(v);
    }
    const int jp = (c4 * 8) ^ swz8(n);          // XOR permutes 16B blocks, keeps 8B phase
    *(ushort4*)(tb + n * 128 + jp) = make_ushort4(he[0], he[1], he[2], he[3]);
  }
}

// ---------------- GEMM: 128x480 tile, BK=64, 8 waves (4m x 2n), split-K ----------------
__global__ __launch_bounds__(512, 2) void hs_gemm(
    const float* __restrict__ x, const unsigned char* __restrict__ wt,
    float* __restrict__ partials, int ksplit, int tpc) {
  extern __shared__ __align__(16) unsigned char smem[];
  const int bid   = blockIdx.x;
  const int chunk = bid % ksplit;            // same-chunk blocks cluster on XCDs (wt L2 reuse)
  const int mtile = bid / ksplit;
  const int t0 = chunk * tpc;
  int t1 = t0 + tpc; if (t1 > NT) t1 = NT;
  const int m0 = mtile * BM;
  const int tid = threadIdx.x;
  const int lane = tid & 63, wid = tid >> 6;
  const int wm = wid >> 1, wn = wid & 1;     // wave tile: 32 rows x 240 cols
  const int jl  = (lane >> 4) * 16;          // frag k-offset bytes within a 64B k-half
  const int l15 = lane & 15;

  // A staging geometry: thread covers row tid>>2, 16 k-elems at (tid&3)*16
  const int arow = tid >> 2, c16 = tid & 3;
  const float* xr = x + (size_t)(m0 + arow) * KDIM + c16 * 16;

  f32x4 acc[2][15];
#pragma unroll
  for (int mf = 0; mf < 2; ++mf)
#pragma unroll
    for (int nf = 0; nf < 15; ++nf)
      acc[mf][nf] = f32x4{0.f, 0.f, 0.f, 0.f};

  auto stageB = [&](int kt, int buf) {   // 60 x 1KB wave-chunks, pre-swizzled in ws
    const unsigned char* src = wt + (size_t)kt * TILE_B + lane * 16;
    unsigned char* dstb = smem + buf * BUF_B;
#pragma unroll
    for (int c = 0; c < 8; ++c) {
      const int cc = wid + c * 8;
      if (cc < 60) {
        __builtin_amdgcn_global_load_lds(
            (const __attribute__((address_space(1))) unsigned int*)(src + cc * 1024),
            (__attribute__((address_space(3))) unsigned int*)(dstb + cc * 1024),
            16, 0, 0);
      }
    }
  };

  auto loadA = [&](int kt, f32x4& v0, f32x4& v1, f32x4& v2, f32x4& v3) {
    const int kb = kt * BK + c16 * 16;
    const float* p = xr + (size_t)kt * BK;
    if (kb + 16 <= KDIM) {
      __builtin_memcpy(&v0, p, 16);      __builtin_memcpy(&v1, p + 4, 16);
      __builtin_memcpy(&v2, p + 8, 16);  __builtin_memcpy(&v3, p + 12, 16);
    } else {                              // only the last K-tile takes this path
#pragma unroll
      for (int e = 0; e < 4; ++e) {
        v0[e] = (kb + e < KDIM)      ? p[e]      : 0.f;
        v1[e] = (kb + 4 + e < KDIM)  ? p[4 + e]  : 0.f;
        v2[e] = (kb + 8 + e < KDIM)  ? p[8 + e]  : 0.f;
        v3[e] = (kb + 12 + e < KDIM) ? p[12 + e] : 0.f;
      }
    }
  };

  auto writeA = [&](int buf, const f32x4& v0, const f32x4& v1,
                    const f32x4& v2, const f32x4& v3) {
    unsigned char* ab = smem + buf * BUF_B + TILE_B + arow * 128;
    unsigned short he[16];
#pragma unroll
    for (int e = 0; e < 4; ++e) {
      he[e]      = f2h(v0[e]);
      he[4 + e]  = f2h(v1[e]);
      he[8 + e]  = f2h(v2[e]);
      he[12 + e] = f2h(v3[e]);
    }
    const int s = swz8(arow);
    __builtin_memcpy(ab + ((c16 * 32) ^ s),      he,     16);   // ds_write_b128 x2
    __builtin_memcpy(ab + ((c16 * 32 + 16) ^ s), he + 8, 16);
  };

  auto compute = [&](int buf) {          // flat block: compiler pipelines ds_read/MFMA
    const unsigned char* bb = smem + buf * BUF_B;
    const unsigned char* ab = bb + TILE_B;
#pragma unroll
    for (int ks = 0; ks < 2; ++ks) {     // two K=32 sub-steps per 64-wide tile
      const int kbyte = ks * 64 + jl;
      f16x8 ah[2];
#pragma unroll
      for (int mf = 0; mf < 2; ++mf) {
        const int m = wm * 32 + mf * 16 + l15;
        ah[mf] = *(const f16x8*)(ab + m * 128 + (kbyte ^ swz8(m)));
      }
#pragma unroll
      for (int nf = 0; nf < 15; ++nf) {
        const int n = wn * 240 + nf * 16 + l15;
        const f16x8 bw = *(const f16x8*)(bb + n * 128 + (kbyte ^ swz8(n)));
        acc[0][nf] = __builtin_amdgcn_mfma_f32_16x16x32_f16(ah[0], bw, acc[0][nf], 0, 0, 0);
        acc[1][nf] = __builtin_amdgcn_mfma_f32_16x16x32_f16(ah[1], bw, acc[1][nf], 0, 0, 0);
      }
    }
  };

  if (t0 < t1) {
    f32x4 v0, v1, v2, v3;
    stageB(t0, 0);
    loadA(t0, v0, v1, v2, v3);
    writeA(0, v0, v1, v2, v3);          // implicit vmcnt wait on own loads
    __syncthreads();
    int buf = 0;
    for (int t = t0; t < t1; ++t) {
      const bool more = (t + 1 < t1);
      if (more) {                       // prefetch next tile before compute (2-phase)
        stageB(t + 1, buf ^ 1);
        loadA(t + 1, v0, v1, v2, v3);
      }
      compute(buf);
      if (more) writeA(buf ^ 1, v0, v1, v2, v3);
      __syncthreads();
      buf ^= 1;
    }
  }

  // epilogue: C/D frag map (m89): lane l, reg r -> row=(l>>4)*4+r, col=l&15
  float* pout = partials + ((size_t)chunk * BATCH + m0) * NPAD;
#pragma unroll
  for (int mf = 0; mf < 2; ++mf)
#pragma unroll
    for (int nf = 0; nf < 15; ++nf)
#pragma unroll
      for (int r = 0; r < 4; ++r) {
        const int row = wm * 32 + mf * 16 + (lane >> 4) * 4 + r;
        const int col = wn * 240 + nf * 16 + l15;
        pout[(size_t)row * NPAD + col] = acc[mf][nf][r];
      }
}

// ---------------- finish: reduce + bias + softmax x2 + outer-product store ----------------
__global__ __launch_bounds__(512) void hs_finish(
    const float* __restrict__ partials, const float* __restrict__ b0,
    const float* __restrict__ b1, float* __restrict__ out, int ksplit) {
  const int b = blockIdx.x;
  __shared__ float lg[NPAD];
  __shared__ float red[4];          // {max0, 1/sum0, max1, 1/sum1}
  const int tid = threadIdx.x;
  if (tid < NPAD) {
    float v = 0.f;
    for (int c = 0; c < ksplit; ++c)
      v += partials[((size_t)c * BATCH + b) * NPAD + tid];
    v *= (1.0f / WSCALE);           // undo W pre-scale
    if (tid < LSZ) v += b0[tid];
    else if (tid >= HOFF && tid < HOFF + LSZ) v += b1[tid - HOFF];
    lg[tid] = v;
  }
  __syncthreads();
  const int wid = tid >> 6, lane = tid & 63;
  if (wid < 2) {                    // wave 0 -> head0, wave 1 -> head1
    const int base = wid * HOFF;
    float m = -1e30f;
    for (int i = lane; i < LSZ; i += 64) m = fmaxf(m, lg[base + i]);
#pragma unroll
    for (int s = 32; s; s >>= 1) m = fmaxf(m, __shfl_xor(m, s));
    float sum = 0.f;
    for (int i = lane; i < LSZ; i += 64) sum += __expf(lg[base + i] - m);
#pragma unroll
    for (int s = 32; s; s >>= 1) sum += __shfl_xor(sum, s);
    if (lane == 0) { red[wid * 2] = m; red[wid * 2 + 1] = 1.0f / sum; }
  }
  __syncthreads();
  if (tid < NPAD) {                 // own-index read-modify-write: no extra barrier needed
    const int h = (tid >= HOFF) ? 1 : 0;
    const int off = tid - (h ? HOFF : 0);
    float hv = 0.f;
    if (off < LSZ) hv = __expf(lg[tid] - red[2 * h]) * red[2 * h + 1];
    lg[tid] = hv;
  }
  __syncthreads();
  const size_t ob = (size_t)b * KDIM;
  for (int f = tid; f < KDIM; f += 512) {
    const int i = f / LSZ;          // compiler magic-mul; stride-1 LDS reads (conflict-free)
    const int j = f - i * LSZ;
    out[ob + f] = lg[i] * lg[HOFF + j];
  }
}

extern "C" void kernel_launch(void* const* d_in, const int* in_sizes, int n_in,
                              void* d_out, int out_size, void* d_ws, size_t ws_size,
                              hipStream_t stream) {
  (void)in_sizes; (void)n_in; (void)out_size;
  const float* x  = (const float*)d_in[0];
  const float* W0 = (const float*)d_in[1];
  const float* W1 = (const float*)d_in[2];
  const float* b0 = (const float*)d_in[3];
  const float* b1 = (const float*)d_in[4];
  float* out = (float*)d_out;
  unsigned char* ws = (unsigned char*)d_ws;

  const size_t WT_BYTES  = (size_t)NT * TILE_B;            // 48.3 MB
  const size_t PER_CHUNK = (size_t)BATCH * NPAD * sizeof(float);
  int ksplit = 16;
  if (ws_size > WT_BYTES) {
    const int kmax = (int)((ws_size - WT_BYTES) / PER_CHUNK);
    if (ksplit > kmax) ksplit = kmax;
  } else {
    ksplit = 1;
  }
  if (ksplit < 1) ksplit = 1;
  float* partials = (float*)(ws + WT_BYTES);
  const int tpc = (NT + ksplit - 1) / ksplit;

  hs_prep<<<dim3(NT), dim3(512), 0, stream>>>(W0, W1, ws);
  hipFuncSetAttribute((const void*)hs_gemm,
                      hipFuncAttributeMaxDynamicSharedMemorySize, LDS_TOT);
  hs_gemm<<<dim3(16 * ksplit), dim3(512), LDS_TOT, stream>>>(x, ws, partials, ksplit, tpc);
  hs_finish<<<dim3(BATCH), dim3(512), 0, stream>>>(partials, b0, b1, out, ksplit);
}